// Round 6
// baseline (122.079 us; speedup 1.0000x reference)
//
#include <hip/hip_runtime.h>
#include <stdint.h>

// ScatterND (k=1): out = data.copy(); out[indices[i]] = updates[i]
// data: [1000000,64] f32   indices: [100000,1] i32   updates: [100000,64] f32
//
// R6: isolate the copy. Nontemporal load+store (bypass L2 alloc for the
// 512 MB stream vs 32 MB L2) + 8-deep MLP (8 independent loads issued
// before any store). Scatter unchanged. If this is neutral vs R5's
// hipMemcpyAsync, the ~5 TB/s mixed r+w ceiling is confirmed -> roofline.

typedef float f32x4 __attribute__((ext_vector_type(4)));

__global__ __launch_bounds__(256) void copy_nt_kernel(
    const f32x4* __restrict__ src, f32x4* __restrict__ dst, size_t n4) {
    const size_t stride = (size_t)gridDim.x * blockDim.x;
    size_t i = (size_t)blockIdx.x * blockDim.x + threadIdx.x;
    for (; i + 7 * stride < n4; i += 8 * stride) {
        f32x4 v0 = __builtin_nontemporal_load(src + i);
        f32x4 v1 = __builtin_nontemporal_load(src + i + stride);
        f32x4 v2 = __builtin_nontemporal_load(src + i + 2 * stride);
        f32x4 v3 = __builtin_nontemporal_load(src + i + 3 * stride);
        f32x4 v4 = __builtin_nontemporal_load(src + i + 4 * stride);
        f32x4 v5 = __builtin_nontemporal_load(src + i + 5 * stride);
        f32x4 v6 = __builtin_nontemporal_load(src + i + 6 * stride);
        f32x4 v7 = __builtin_nontemporal_load(src + i + 7 * stride);
        __builtin_nontemporal_store(v0, dst + i);
        __builtin_nontemporal_store(v1, dst + i + stride);
        __builtin_nontemporal_store(v2, dst + i + 2 * stride);
        __builtin_nontemporal_store(v3, dst + i + 3 * stride);
        __builtin_nontemporal_store(v4, dst + i + 4 * stride);
        __builtin_nontemporal_store(v5, dst + i + 5 * stride);
        __builtin_nontemporal_store(v6, dst + i + 6 * stride);
        __builtin_nontemporal_store(v7, dst + i + 7 * stride);
    }
    for (; i < n4; i += stride) {
        __builtin_nontemporal_store(__builtin_nontemporal_load(src + i), dst + i);
    }
}

__global__ __launch_bounds__(256) void scatter_kernel(
    const int* __restrict__ idx,
    const f32x4* __restrict__ upd,
    f32x4* __restrict__ out,
    size_t total4) {
    size_t i = (size_t)blockIdx.x * blockDim.x + threadIdx.x;
    const size_t stride = (size_t)gridDim.x * blockDim.x;
    for (; i < total4; i += stride) {
        const size_t row = i >> 4;
        const size_t col = i & 15;
        const int r = idx[row];
        out[(size_t)r * 16 + col] = upd[i];
    }
}

extern "C" void kernel_launch(void* const* d_in, const int* in_sizes, int n_in,
                              void* d_out, int out_size, void* d_ws, size_t ws_size,
                              hipStream_t stream) {
    const float* data    = (const float*)d_in[0];
    const int*   indices = (const int*)d_in[1];
    const float* updates = (const float*)d_in[2];
    float* out = (float*)d_out;

    const size_t n4          = (size_t)out_size / 4;      // 16M float4
    const size_t num_updates = (size_t)in_sizes[2] / 64;  // 100,000
    const size_t total4      = num_updates * 16;          // 1.6M float4

    const int block = 256;
    size_t gc = (n4 + block - 1) / block;
    if (gc > 2048) gc = 2048;
    size_t gs = (total4 + block - 1) / block;
    if (gs > 2048) gs = 2048;

    copy_nt_kernel<<<(int)gc, block, 0, stream>>>(
        (const f32x4*)data, (f32x4*)out, n4);
    scatter_kernel<<<(int)gs, block, 0, stream>>>(
        indices, (const f32x4*)updates, (f32x4*)out, total4);
}